// Round 1
// baseline (960.990 us; speedup 1.0000x reference)
//
#include <hip/hip_runtime.h>
#include <hip/hip_bf16.h>

// Problem: B=4, S=2048, E=512, H=8, D=64, F=2048
// out = MLP(GELU) ( attn(softmax(-(Q-K)^2/8)) @ V ) + input1
// All fp32 this round (baseline). h intermediate stored bf16.

#define Bsz 4
#define Ssz 2048
#define Esz 512
#define Hsz 8
#define Dsz 64
#define Fsz 2048

static __device__ __forceinline__ float bcast_lane(float v, int l) {
    return __int_as_float(__builtin_amdgcn_readlane(__float_as_int(v), l));
}

// ---------------- K1: LayerNorm + Q/K/V projections, one block per token ----------------
__global__ __launch_bounds__(256) void ln_qkv_kernel(
    const float* __restrict__ x,   // [B,S,E]
    const float* __restrict__ Wv,  // [H,D,D]  (din,dout)
    const float* __restrict__ bv,  // [H,D]
    const float* __restrict__ Wq,  // [H,D]
    const float* __restrict__ bq,  // [H]
    const float* __restrict__ Wk,  // [H,D]
    const float* __restrict__ bk,  // [H]
    float* __restrict__ Qo,        // [B*H,S]
    float* __restrict__ Ko,        // [B*H,S]
    float* __restrict__ Vo)        // [B*H,S,D]
{
    int tok = blockIdx.x;              // b*S + s
    int b = tok >> 11, s = tok & 2047;
    int t = threadIdx.x;

    __shared__ float xn[512];
    __shared__ float red[256];

    const float* xrow = x + (size_t)tok * Esz;
    float x0 = xrow[t], x1 = xrow[t + 256];

    red[t] = x0 + x1;
    __syncthreads();
    for (int o = 128; o > 0; o >>= 1) { if (t < o) red[t] += red[t + o]; __syncthreads(); }
    float mean = red[0] * (1.0f / 512.0f);
    __syncthreads();
    float d0 = x0 - mean, d1 = x1 - mean;
    red[t] = d0 * d0 + d1 * d1;
    __syncthreads();
    for (int o = 128; o > 0; o >>= 1) { if (t < o) red[t] += red[t + o]; __syncthreads(); }
    float inv = rsqrtf(red[0] * (1.0f / 512.0f) + 1e-5f);

    xn[t] = d0 * inv;
    xn[t + 256] = d1 * inv;
    __syncthreads();

    // V projection: 512 outputs, 2 per thread
    #pragma unroll
    for (int rep = 0; rep < 2; ++rep) {
        int o = t + rep * 256;           // h*64 + dout
        int h = o >> 6, dd = o & 63;
        const float* w = Wv + (size_t)(h * 64) * 64 + dd;  // Wv[h][e][dd], stride 64
        const float* xh = xn + h * 64;
        float acc = bv[o];
        #pragma unroll
        for (int e = 0; e < 64; ++e) acc = fmaf(xh[e], w[(size_t)e * 64], acc);
        Vo[((size_t)(b * Hsz + h) * Ssz + s) * Dsz + dd] = acc;
    }

    // Q/K scalars: threads 0..15 (t<8 -> Q head t, t>=8 -> K head t-8)
    if (t < 16) {
        int h = t & 7;
        const float* w = (t < 8 ? Wq : Wk) + h * 64;
        const float* xh = xn + h * 64;
        float acc = 0.0f;
        #pragma unroll
        for (int e = 0; e < 64; ++e) acc = fmaf(xh[e], w[e], acc);
        acc += (t < 8 ? bq[h] : bk[h]);
        float* outp = (t < 8 ? Qo : Ko);
        outp[(b * Hsz + h) * Ssz + s] = acc;
    }
}

// ---------------- K2: attention. block=256 (4 waves), wave handles 4 q, lane = d ----------------
__global__ __launch_bounds__(256) void attn_kernel(
    const float* __restrict__ Qv,  // [B*H,S]
    const float* __restrict__ Kv,  // [B*H,S]
    const float* __restrict__ Vv,  // [B*H,S,D]
    float* __restrict__ ho)        // [B,S,H,D] == [B,S,E]
{
    int lane = threadIdx.x & 63;
    int w = threadIdx.x >> 6;
    int bh = blockIdx.y;                    // 0..31
    int qbase = (blockIdx.x * 4 + w) * 4;   // 4 q per wave
    int b = bh >> 3, h = bh & 7;

    const float* Kb = Kv + bh * Ssz;
    const float* Vb = Vv + (size_t)bh * Ssz * Dsz;
    const float* Qb = Qv + bh * Ssz;

    float q0 = Qb[qbase + 0];
    float q1 = Qb[qbase + 1];
    float q2 = Qb[qbase + 2];
    float q3 = Qb[qbase + 3];

    float acc0 = 0.f, acc1 = 0.f, acc2 = 0.f, acc3 = 0.f;
    float den0 = 0.f, den1 = 0.f, den2 = 0.f, den3 = 0.f;

    for (int kt = 0; kt < Ssz; kt += 64) {
        float Kk = Kb[kt + lane];
        float t0 = q0 - Kk, t1 = q1 - Kk, t2 = q2 - Kk, t3 = q3 - Kk;
        float e0 = __expf(t0 * t0 * -0.125f);
        float e1 = __expf(t1 * t1 * -0.125f);
        float e2 = __expf(t2 * t2 * -0.125f);
        float e3 = __expf(t3 * t3 * -0.125f);
        den0 += e0; den1 += e1; den2 += e2; den3 += e3;
        const float* vp = Vb + (size_t)kt * Dsz + lane;
        #pragma unroll
        for (int j = 0; j < 64; ++j) {
            float v = vp[(size_t)j * Dsz];
            acc0 = fmaf(bcast_lane(e0, j), v, acc0);
            acc1 = fmaf(bcast_lane(e1, j), v, acc1);
            acc2 = fmaf(bcast_lane(e2, j), v, acc2);
            acc3 = fmaf(bcast_lane(e3, j), v, acc3);
        }
    }
    // reduce denominators across lanes (each lane holds partial over its k's)
    #pragma unroll
    for (int off = 32; off > 0; off >>= 1) {
        den0 += __shfl_xor(den0, off);
        den1 += __shfl_xor(den1, off);
        den2 += __shfl_xor(den2, off);
        den3 += __shfl_xor(den3, off);
    }
    size_t base = ((size_t)(b * Ssz + qbase) * Hsz + h) * Dsz + lane;
    ho[base + 0 * Hsz * Dsz] = acc0 / den0;
    ho[base + 1 * Hsz * Dsz] = acc1 / den1;
    ho[base + 2 * Hsz * Dsz] = acc2 / den2;
    ho[base + 3 * Hsz * Dsz] = acc3 / den3;
}

// ---------------- K3: mlp1: h = gelu(ho @ W1 + b1), out bf16. M=8192 K=512 N=2048 ----------------
__global__ __launch_bounds__(256) void mlp1_kernel(
    const float* __restrict__ A,       // [8192,512]
    const float* __restrict__ W,       // [512,2048]
    const float* __restrict__ bias,    // [2048]
    __hip_bfloat16* __restrict__ Hout) // [8192,2048]
{
    __shared__ float As[64][20];   // [m][k], padded
    __shared__ float Bs[16][68];   // [k][n], padded

    int t = threadIdx.x;
    int tx = t & 15, ty = t >> 4;
    int bn = blockIdx.x * 64, bm = blockIdx.y * 64;

    float acc[4][4] = {};

    for (int k0 = 0; k0 < 512; k0 += 16) {
        {
            int r = t >> 2, c = (t & 3) * 4;
            float4 av = *(const float4*)&A[(size_t)(bm + r) * 512 + k0 + c];
            *(float4*)&As[r][c] = av;
        }
        {
            int col = t & 63, rw = t >> 6;
            #pragma unroll
            for (int i = 0; i < 4; ++i)
                Bs[rw + 4 * i][col] = W[(size_t)(k0 + rw + 4 * i) * 2048 + bn + col];
        }
        __syncthreads();
        #pragma unroll
        for (int kk = 0; kk < 16; ++kk) {
            float a0 = As[ty * 4 + 0][kk];
            float a1 = As[ty * 4 + 1][kk];
            float a2 = As[ty * 4 + 2][kk];
            float a3 = As[ty * 4 + 3][kk];
            float4 bv4 = *(const float4*)&Bs[kk][tx * 4];
            acc[0][0] = fmaf(a0, bv4.x, acc[0][0]); acc[0][1] = fmaf(a0, bv4.y, acc[0][1]);
            acc[0][2] = fmaf(a0, bv4.z, acc[0][2]); acc[0][3] = fmaf(a0, bv4.w, acc[0][3]);
            acc[1][0] = fmaf(a1, bv4.x, acc[1][0]); acc[1][1] = fmaf(a1, bv4.y, acc[1][1]);
            acc[1][2] = fmaf(a1, bv4.z, acc[1][2]); acc[1][3] = fmaf(a1, bv4.w, acc[1][3]);
            acc[2][0] = fmaf(a2, bv4.x, acc[2][0]); acc[2][1] = fmaf(a2, bv4.y, acc[2][1]);
            acc[2][2] = fmaf(a2, bv4.z, acc[2][2]); acc[2][3] = fmaf(a2, bv4.w, acc[2][3]);
            acc[3][0] = fmaf(a3, bv4.x, acc[3][0]); acc[3][1] = fmaf(a3, bv4.y, acc[3][1]);
            acc[3][2] = fmaf(a3, bv4.z, acc[3][2]); acc[3][3] = fmaf(a3, bv4.w, acc[3][3]);
        }
        __syncthreads();
    }

    #pragma unroll
    for (int i = 0; i < 4; ++i) {
        int m = bm + ty * 4 + i;
        #pragma unroll
        for (int j = 0; j < 4; ++j) {
            int n = bn + tx * 4 + j;
            float v = acc[i][j] + bias[n];
            float g = 0.5f * v * (1.0f + erff(v * 0.70710678118654752f));
            Hout[(size_t)m * 2048 + n] = __float2bfloat16(g);
        }
    }
}

// ---------------- K4: mlp2: out = h @ W2 + b2 + input1. M=8192 K=2048 N=512 ----------------
__global__ __launch_bounds__(256) void mlp2_kernel(
    const __hip_bfloat16* __restrict__ Ah, // [8192,2048]
    const float* __restrict__ W,           // [2048,512]
    const float* __restrict__ bias,        // [512]
    const float* __restrict__ resid,       // [8192,512]
    float* __restrict__ Out)               // [8192,512]
{
    __shared__ float As[64][20];
    __shared__ float Bs[16][68];

    int t = threadIdx.x;
    int tx = t & 15, ty = t >> 4;
    int bn = blockIdx.x * 64, bm = blockIdx.y * 64;

    float acc[4][4] = {};

    for (int k0 = 0; k0 < 2048; k0 += 16) {
        {
            int r = t >> 2, c = (t & 3) * 4;
            unsigned long long raw = *(const unsigned long long*)&Ah[(size_t)(bm + r) * 2048 + k0 + c];
            #pragma unroll
            for (int j = 0; j < 4; ++j) {
                unsigned int u = (unsigned int)(raw >> (16 * j)) & 0xFFFFu;
                As[r][c + j] = __int_as_float((int)(u << 16));
            }
        }
        {
            int col = t & 63, rw = t >> 6;
            #pragma unroll
            for (int i = 0; i < 4; ++i)
                Bs[rw + 4 * i][col] = W[(size_t)(k0 + rw + 4 * i) * 512 + bn + col];
        }
        __syncthreads();
        #pragma unroll
        for (int kk = 0; kk < 16; ++kk) {
            float a0 = As[ty * 4 + 0][kk];
            float a1 = As[ty * 4 + 1][kk];
            float a2 = As[ty * 4 + 2][kk];
            float a3 = As[ty * 4 + 3][kk];
            float4 bv4 = *(const float4*)&Bs[kk][tx * 4];
            acc[0][0] = fmaf(a0, bv4.x, acc[0][0]); acc[0][1] = fmaf(a0, bv4.y, acc[0][1]);
            acc[0][2] = fmaf(a0, bv4.z, acc[0][2]); acc[0][3] = fmaf(a0, bv4.w, acc[0][3]);
            acc[1][0] = fmaf(a1, bv4.x, acc[1][0]); acc[1][1] = fmaf(a1, bv4.y, acc[1][1]);
            acc[1][2] = fmaf(a1, bv4.z, acc[1][2]); acc[1][3] = fmaf(a1, bv4.w, acc[1][3]);
            acc[2][0] = fmaf(a2, bv4.x, acc[2][0]); acc[2][1] = fmaf(a2, bv4.y, acc[2][1]);
            acc[2][2] = fmaf(a2, bv4.z, acc[2][2]); acc[2][3] = fmaf(a2, bv4.w, acc[2][3]);
            acc[3][0] = fmaf(a3, bv4.x, acc[3][0]); acc[3][1] = fmaf(a3, bv4.y, acc[3][1]);
            acc[3][2] = fmaf(a3, bv4.z, acc[3][2]); acc[3][3] = fmaf(a3, bv4.w, acc[3][3]);
        }
        __syncthreads();
    }

    #pragma unroll
    for (int i = 0; i < 4; ++i) {
        int m = bm + ty * 4 + i;
        #pragma unroll
        for (int j = 0; j < 4; ++j) {
            int n = bn + tx * 4 + j;
            size_t idx = (size_t)m * 512 + n;
            Out[idx] = acc[i][j] + bias[n] + resid[idx];
        }
    }
}

extern "C" void kernel_launch(void* const* d_in, const int* in_sizes, int n_in,
                              void* d_out, int out_size, void* d_ws, size_t ws_size,
                              hipStream_t stream) {
    const float* x  = (const float*)d_in[0];
    const float* Wv = (const float*)d_in[1];
    const float* bv = (const float*)d_in[2];
    const float* Wq = (const float*)d_in[3];
    const float* bq = (const float*)d_in[4];
    const float* Wk = (const float*)d_in[5];
    const float* bk = (const float*)d_in[6];
    const float* W1 = (const float*)d_in[7];
    const float* b1 = (const float*)d_in[8];
    const float* W2 = (const float*)d_in[9];
    const float* b2 = (const float*)d_in[10];
    float* out = (float*)d_out;

    char* ws = (char*)d_ws;
    // layout: Q[65536 f32] K[65536 f32] V[4194304 f32] ho[4194304 f32] h[16777216 bf16]
    float* Qb = (float*)(ws);
    float* Kb = (float*)(ws + 262144);
    float* Vb = (float*)(ws + 524288);
    float* ho = (float*)(ws + 524288 + 16777216);
    __hip_bfloat16* hbuf = (__hip_bfloat16*)(ws + 524288 + 2 * 16777216);

    ln_qkv_kernel<<<dim3(Bsz * Ssz), dim3(256), 0, stream>>>(x, Wv, bv, Wq, bq, Wk, bk, Qb, Kb, Vb);
    attn_kernel<<<dim3(Ssz / 16, Bsz * Hsz), dim3(256), 0, stream>>>(Qb, Kb, Vb, ho);
    mlp1_kernel<<<dim3(Fsz / 64, (Bsz * Ssz) / 64), dim3(256), 0, stream>>>(ho, W1, b1, hbuf);
    mlp2_kernel<<<dim3(Esz / 64, (Bsz * Ssz) / 64), dim3(256), 0, stream>>>(hbuf, W2, b2, x, out);
}

// Round 2
// 243.231 us; speedup vs baseline: 3.9509x; 3.9509x over previous
//
#include <hip/hip_runtime.h>
#include <hip/hip_bf16.h>

// B=4, S=2048, E=512, H=8, D=64, F=2048
// Attention via exact Gaussian-kernel Taylor factorization (R=16 terms):
//   exp(-(q-k)^2/8) = e^{-q^2/8} e^{-k^2/8} sum_n phi_n(q) phi_n(k),  phi_n(t)=(t/2)^n/sqrt(n!)
//   e^{-q^2/8} cancels in softmax ratio. |qk/4| <~ 2.1 -> R=16 remainder ~7e-9.
// MLP via bf16 MFMA (16x16x32), 128x128 tile, BK=32, global_load_lds w16 (m97 structure).

#define Bsz 4
#define Ssz 2048
#define Esz 512
#define Hsz 8
#define Dsz 64
#define Fsz 2048
#define NR 16   // Taylor terms

typedef __attribute__((ext_vector_type(8))) short bf16x8;
typedef __attribute__((ext_vector_type(4))) float f32x4;

// 1/sqrt(n), n=1..15 (RS[0] unused)
__device__ __constant__ float RS[16] = {
    0.f, 1.0f, 0.70710678f, 0.57735027f, 0.5f, 0.44721360f, 0.40824829f,
    0.37796447f, 0.35355339f, 0.33333333f, 0.31622777f, 0.30151134f,
    0.28867513f, 0.27735010f, 0.26726124f, 0.25819889f};

static __device__ __forceinline__ void gload_lds16(const void* g, void* l) {
    __builtin_amdgcn_global_load_lds(
        (const __attribute__((address_space(1))) unsigned int*)g,
        (__attribute__((address_space(3))) unsigned int*)l, 16, 0, 0);
}

// ---------------- K1: LayerNorm + Q/K/V projections, one block per token ----------------
__global__ __launch_bounds__(256) void ln_qkv_kernel(
    const float* __restrict__ x,
    const float* __restrict__ Wv, const float* __restrict__ bv,
    const float* __restrict__ Wq, const float* __restrict__ bq,
    const float* __restrict__ Wk, const float* __restrict__ bk,
    float* __restrict__ Qo, float* __restrict__ Ko, float* __restrict__ Vo)
{
    int tok = blockIdx.x;
    int b = tok >> 11, s = tok & 2047;
    int t = threadIdx.x;

    __shared__ float xn[512];
    __shared__ float red[256];

    const float* xrow = x + (size_t)tok * Esz;
    float x0 = xrow[t], x1 = xrow[t + 256];

    red[t] = x0 + x1;
    __syncthreads();
    for (int o = 128; o > 0; o >>= 1) { if (t < o) red[t] += red[t + o]; __syncthreads(); }
    float mean = red[0] * (1.0f / 512.0f);
    __syncthreads();
    float d0 = x0 - mean, d1 = x1 - mean;
    red[t] = d0 * d0 + d1 * d1;
    __syncthreads();
    for (int o = 128; o > 0; o >>= 1) { if (t < o) red[t] += red[t + o]; __syncthreads(); }
    float inv = rsqrtf(red[0] * (1.0f / 512.0f) + 1e-5f);

    xn[t] = d0 * inv;
    xn[t + 256] = d1 * inv;
    __syncthreads();

    #pragma unroll
    for (int rep = 0; rep < 2; ++rep) {
        int o = t + rep * 256;
        int h = o >> 6, dd = o & 63;
        const float* w = Wv + (size_t)(h * 64) * 64 + dd;
        const float* xh = xn + h * 64;
        float acc = bv[o];
        #pragma unroll
        for (int e = 0; e < 64; ++e) acc = fmaf(xh[e], w[(size_t)e * 64], acc);
        Vo[((size_t)(b * Hsz + h) * Ssz + s) * Dsz + dd] = acc;
    }

    if (t < 16) {
        int h = t & 7;
        const float* w = (t < 8 ? Wq : Wk) + h * 64;
        const float* xh = xn + h * 64;
        float acc = 0.0f;
        #pragma unroll
        for (int e = 0; e < 64; ++e) acc = fmaf(xh[e], w[e], acc);
        acc += (t < 8 ? bq[h] : bk[h]);
        float* outp = (t < 8 ? Qo : Ko);
        outp[(b * Hsz + h) * Ssz + s] = acc;
    }
}

// ---------------- K2a: K-side moments, partial over k-chunks ----------------
// Mp[bh][chunk][n][68]: cols 0..63 = sum_k w_n(k) V[k,d]; col 64 = sum_k w_n(k)
__global__ __launch_bounds__(256) void attn_moments(
    const float* __restrict__ Kv, const float* __restrict__ Vv, float* __restrict__ Mp)
{
    int chunk = blockIdx.x, bh = blockIdx.y;
    int t = threadIdx.x;
    __shared__ float Wt[256][16];
    __shared__ float denp[4][16];

    int kg = chunk * 256 + t;
    float kv = Kv[bh * Ssz + kg];
    float wn = __expf(-0.125f * kv * kv);   // e^{-k^2/8}
    float half = 0.5f * kv;
    Wt[t][0] = wn;
    #pragma unroll
    for (int n = 1; n < NR; ++n) { wn *= half * RS[n]; Wt[t][n] = wn; }
    __syncthreads();

    int w = t >> 6, lane = t & 63;
    int ng = w * 4;
    float a0 = 0.f, a1 = 0.f, a2 = 0.f, a3 = 0.f;
    const float* vbase = Vv + ((size_t)bh * Ssz + chunk * 256) * Dsz + lane;
    for (int k = 0; k < 256; ++k) {
        float v = vbase[(size_t)k * Dsz];
        a0 = fmaf(Wt[k][ng + 0], v, a0);
        a1 = fmaf(Wt[k][ng + 1], v, a1);
        a2 = fmaf(Wt[k][ng + 2], v, a2);
        a3 = fmaf(Wt[k][ng + 3], v, a3);
    }
    size_t base = (((size_t)bh * 8 + chunk) * NR + ng) * 68 + lane;
    Mp[base + 0 * 68] = a0;
    Mp[base + 1 * 68] = a1;
    Mp[base + 2 * 68] = a2;
    Mp[base + 3 * 68] = a3;

    if (lane < 16) {
        float s = 0.f;
        for (int kk = 0; kk < 64; ++kk) s += Wt[w * 64 + kk][lane];
        denp[w][lane] = s;
    }
    __syncthreads();
    if (t < 16) {
        float m = denp[0][t] + denp[1][t] + denp[2][t] + denp[3][t];
        Mp[(((size_t)bh * 8 + chunk) * NR + t) * 68 + 64] = m;
    }
}

// ---------------- K2b: reduce chunk partials ----------------
__global__ __launch_bounds__(256) void attn_reduce(
    const float* __restrict__ Mp, float* __restrict__ M)
{
    int bh = blockIdx.x, t = threadIdx.x;
    for (int i = t; i < NR * 68; i += 256) {
        float s = 0.f;
        #pragma unroll
        for (int c = 0; c < 8; ++c)
            s += Mp[(((size_t)bh * 8 + c) * NR) * 68 + i];
        M[(size_t)bh * NR * 68 + i] = s;
    }
}

// ---------------- K2c: apply Q-side, write head_out as bf16 [8192,512] ----------------
__global__ __launch_bounds__(256) void attn_apply(
    const float* __restrict__ Qv, const float* __restrict__ M, __hip_bfloat16* __restrict__ A1)
{
    int tok = blockIdx.x;
    int b = tok >> 11, s = tok & 2047;
    int t = threadIdx.x;
    #pragma unroll
    for (int rep = 0; rep < 2; ++rep) {
        int e = t + rep * 256;
        int h = e >> 6, d = e & 63;
        int bh = b * 8 + h;
        float q = Qv[bh * Ssz + s];
        const float* Mb = M + (size_t)bh * NR * 68;
        float half = 0.5f * q;
        float phi = 1.0f;
        float num = Mb[d], den = Mb[64];
        #pragma unroll
        for (int n = 1; n < NR; ++n) {
            phi *= half * RS[n];
            num = fmaf(phi, Mb[n * 68 + d], num);
            den = fmaf(phi, Mb[n * 68 + 64], den);
        }
        A1[(size_t)tok * Esz + e] = __float2bfloat16(num / den);
    }
}

// ---------------- transpose + fp32->bf16: out[C][R] = in[R][C] ----------------
__global__ __launch_bounds__(256) void transpose_bf16(
    const float* __restrict__ in, __hip_bfloat16* __restrict__ out, int R, int C)
{
    __shared__ float tile[32][33];
    int bx = blockIdx.x, by = blockIdx.y;
    int t = threadIdx.x;
    int tc = t & 31, tr = t >> 5;
    #pragma unroll
    for (int i = 0; i < 4; ++i) {
        int r = by * 32 + tr + i * 8, c = bx * 32 + tc;
        tile[tr + i * 8][tc] = in[(size_t)r * C + c];
    }
    __syncthreads();
    #pragma unroll
    for (int i = 0; i < 4; ++i) {
        int ro = bx * 32 + tr + i * 8, co = by * 32 + tc;
        out[(size_t)ro * R + co] = __float2bfloat16(tile[tc][tr + i * 8]);
    }
}

// ---------------- bf16 MFMA GEMM: C = A[M,K] * Bt[N,K]^T, 128x128 tile, BK=32 ----------------
// EPI=0: out bf16 = gelu(acc + bias). EPI=1: out f32 = acc + bias + resid.
template <int KDIM, int EPI>
__global__ __launch_bounds__(256) void gemm_bf16(
    const __hip_bfloat16* __restrict__ A, const __hip_bfloat16* __restrict__ Bt,
    const float* __restrict__ bias, const float* __restrict__ resid,
    void* __restrict__ Out, int N)
{
    __shared__ unsigned short As[128][32];
    __shared__ unsigned short Bs[128][32];
    int t = threadIdx.x;
    int w = t >> 6, lane = t & 63;
    int wr = w >> 1, wc = w & 1;
    int bm = blockIdx.y * 128, bn = blockIdx.x * 128;

    f32x4 acc[4][4] = {};
    const int r = t >> 2, cg = (t & 3) * 8;

    for (int k0 = 0; k0 < KDIM; k0 += 32) {
        gload_lds16(&A[(size_t)(bm + r) * KDIM + k0 + cg], &As[r][cg]);
        gload_lds16(&A[(size_t)(bm + r + 64) * KDIM + k0 + cg], &As[r + 64][cg]);
        gload_lds16(&Bt[(size_t)(bn + r) * KDIM + k0 + cg], &Bs[r][cg]);
        gload_lds16(&Bt[(size_t)(bn + r + 64) * KDIM + k0 + cg], &Bs[r + 64][cg]);
        __syncthreads();
        bf16x8 af[4], bfr[4];
        #pragma unroll
        for (int i = 0; i < 4; ++i) {
            af[i]  = *(const bf16x8*)&As[wr * 64 + i * 16 + (lane & 15)][(lane >> 4) * 8];
            bfr[i] = *(const bf16x8*)&Bs[wc * 64 + i * 16 + (lane & 15)][(lane >> 4) * 8];
        }
        #pragma unroll
        for (int i = 0; i < 4; ++i)
            #pragma unroll
            for (int j = 0; j < 4; ++j)
                acc[i][j] = __builtin_amdgcn_mfma_f32_16x16x32_bf16(af[i], bfr[j], acc[i][j], 0, 0, 0);
        __syncthreads();
    }

    int col0 = lane & 15, rowg = lane >> 4;
    #pragma unroll
    for (int i = 0; i < 4; ++i) {
        #pragma unroll
        for (int j = 0; j < 4; ++j) {
            #pragma unroll
            for (int v = 0; v < 4; ++v) {
                int m = bm + wr * 64 + i * 16 + rowg * 4 + v;
                int n = bn + wc * 64 + j * 16 + col0;
                float val = acc[i][j][v] + bias[n];
                if (EPI == 0) {
                    float g = 0.5f * val * (1.0f + erff(val * 0.70710678f));
                    ((__hip_bfloat16*)Out)[(size_t)m * N + n] = __float2bfloat16(g);
                } else {
                    size_t idx = (size_t)m * N + n;
                    ((float*)Out)[idx] = val + resid[idx];
                }
            }
        }
    }
}

extern "C" void kernel_launch(void* const* d_in, const int* in_sizes, int n_in,
                              void* d_out, int out_size, void* d_ws, size_t ws_size,
                              hipStream_t stream) {
    const float* x  = (const float*)d_in[0];
    const float* Wv = (const float*)d_in[1];
    const float* bv = (const float*)d_in[2];
    const float* Wq = (const float*)d_in[3];
    const float* bq = (const float*)d_in[4];
    const float* Wk = (const float*)d_in[5];
    const float* bk = (const float*)d_in[6];
    const float* W1 = (const float*)d_in[7];
    const float* b1 = (const float*)d_in[8];
    const float* W2 = (const float*)d_in[9];
    const float* b2 = (const float*)d_in[10];
    float* out = (float*)d_out;

    char* ws = (char*)d_ws;
    float* Qb    = (float*)(ws + 0);               // 256 KB
    float* Kb    = (float*)(ws + 262144);          // 256 KB
    float* Vb    = (float*)(ws + 524288);          // 16 MB
    float* Mpart = (float*)(ws + 17301504);        // 32*8*16*68*4 = 1.06 MB
    float* Mfull = (float*)(ws + 18415616);        // 32*16*68*4
    __hip_bfloat16* A1   = (__hip_bfloat16*)(ws + 18554880);  // 8 MB
    __hip_bfloat16* W1T  = (__hip_bfloat16*)(ws + 26943488);  // 2 MB
    __hip_bfloat16* W2T  = (__hip_bfloat16*)(ws + 29040640);  // 2 MB
    __hip_bfloat16* hbuf = (__hip_bfloat16*)(ws + 31137792);  // 32 MB

    ln_qkv_kernel<<<dim3(Bsz * Ssz), 256, 0, stream>>>(x, Wv, bv, Wq, bq, Wk, bk, Qb, Kb, Vb);
    attn_moments<<<dim3(8, Bsz * Hsz), 256, 0, stream>>>(Kb, Vb, Mpart);
    attn_reduce<<<dim3(Bsz * Hsz), 256, 0, stream>>>(Mpart, Mfull);
    attn_apply<<<dim3(Bsz * Ssz), 256, 0, stream>>>(Qb, Mfull, A1);
    transpose_bf16<<<dim3(Fsz / 32, Esz / 32), 256, 0, stream>>>(W1, W1T, Esz, Fsz);
    transpose_bf16<<<dim3(Esz / 32, Fsz / 32), 256, 0, stream>>>(W2, W2T, Fsz, Esz);
    gemm_bf16<Esz, 0><<<dim3(Fsz / 128, (Bsz * Ssz) / 128), 256, 0, stream>>>(A1, W1T, b1, nullptr, hbuf, Fsz);
    gemm_bf16<Fsz, 1><<<dim3(Esz / 128, (Bsz * Ssz) / 128), 256, 0, stream>>>(hbuf, W2T, b2, x, out, Esz);
}

// Round 3
// 210.089 us; speedup vs baseline: 4.5742x; 1.1577x over previous
//
#include <hip/hip_runtime.h>
#include <hip/hip_bf16.h>

// B=4, S=2048, E=512, H=8, D=64, F=2048
// Attention via exact Gaussian-kernel Taylor factorization (R=16 terms), with the
// V projection folded AFTER the k-sum:  M[n,:] = (sum_k w_n(k) xh[k,:]) @ Wv[h] + den_n*bv.
// MLP via bf16 MFMA (16x16x32), 128x128 tile, BK=32, global_load_lds w16 (m97 structure).

#define Bsz 4
#define Ssz 2048
#define Esz 512
#define Hsz 8
#define Dsz 64
#define Fsz 2048
#define NR 16      // Taylor terms
#define NCH 16     // k-chunks
#define CHK 128    // k per chunk

typedef __attribute__((ext_vector_type(8))) short bf16x8;
typedef __attribute__((ext_vector_type(4))) float f32x4;

// 1/sqrt(n), n=1..15 (RS[0] unused)
__device__ __constant__ float RS[16] = {
    0.f, 1.0f, 0.70710678f, 0.57735027f, 0.5f, 0.44721360f, 0.40824829f,
    0.37796447f, 0.35355339f, 0.33333333f, 0.31622777f, 0.30151134f,
    0.28867513f, 0.27735010f, 0.26726124f, 0.25819889f};

static __device__ __forceinline__ void gload_lds16(const void* g, void* l) {
    __builtin_amdgcn_global_load_lds(
        (const __attribute__((address_space(1))) unsigned int*)g,
        (__attribute__((address_space(3))) unsigned int*)l, 16, 0, 0);
}

static __device__ __forceinline__ unsigned short f2bf(float f) {
    unsigned int b = __float_as_uint(f);
    b += 0x7FFFu + ((b >> 16) & 1u);
    return (unsigned short)(b >> 16);
}

// ---------------- K1: LayerNorm (wave per token) + Q/K scalars + xnorm bf16 ----------------
// Xn layout: [bh][s][d]  (per-head rows, d contiguous)
__global__ __launch_bounds__(256) void ln_qk_kernel(
    const float* __restrict__ x,
    const float* __restrict__ Wq, const float* __restrict__ bq,
    const float* __restrict__ Wk, const float* __restrict__ bk,
    float* __restrict__ Qo, float* __restrict__ Ko, __hip_bfloat16* __restrict__ Xn)
{
    int wid = threadIdx.x >> 6, lane = threadIdx.x & 63;
    int tok = blockIdx.x * 4 + wid;
    int b = tok >> 11, s = tok & 2047;

    const float* xrow = x + (size_t)tok * Esz;
    float4 v0 = *(const float4*)&xrow[lane * 8];
    float4 v1 = *(const float4*)&xrow[lane * 8 + 4];

    float sum = v0.x + v0.y + v0.z + v0.w + v1.x + v1.y + v1.z + v1.w;
    #pragma unroll
    for (int off = 32; off > 0; off >>= 1) sum += __shfl_xor(sum, off);
    float mean = sum * (1.0f / 512.0f);

    float d[8] = {v0.x - mean, v0.y - mean, v0.z - mean, v0.w - mean,
                  v1.x - mean, v1.y - mean, v1.z - mean, v1.w - mean};
    float ss = 0.f;
    #pragma unroll
    for (int j = 0; j < 8; ++j) ss = fmaf(d[j], d[j], ss);
    #pragma unroll
    for (int off = 32; off > 0; off >>= 1) ss += __shfl_xor(ss, off);
    float inv = rsqrtf(ss * (1.0f / 512.0f) + 1e-5f);

    float xn[8];
    #pragma unroll
    for (int j = 0; j < 8; ++j) xn[j] = d[j] * inv;

    // store bf16x8: head h = lane>>3, d0 = (lane&7)*8
    int h = lane >> 3, dsub = (lane & 7) * 8;
    union { bf16x8 v; unsigned short u[8]; } pk;
    #pragma unroll
    for (int j = 0; j < 8; ++j) pk.u[j] = f2bf(xn[j]);
    *(bf16x8*)((unsigned short*)Xn + (((size_t)(b * Hsz + h) * Ssz + s) * Dsz + dsub)) = pk.v;

    // Q/K scalars for head h: partial dot over this lane's 8 elems, reduce over 8-lane group
    float4 wqa = *(const float4*)&Wq[h * 64 + dsub];
    float4 wqb = *(const float4*)&Wq[h * 64 + dsub + 4];
    float4 wka = *(const float4*)&Wk[h * 64 + dsub];
    float4 wkb = *(const float4*)&Wk[h * 64 + dsub + 4];
    float pq = xn[0]*wqa.x + xn[1]*wqa.y + xn[2]*wqa.z + xn[3]*wqa.w
             + xn[4]*wqb.x + xn[5]*wqb.y + xn[6]*wqb.z + xn[7]*wqb.w;
    float pkv = xn[0]*wka.x + xn[1]*wka.y + xn[2]*wka.z + xn[3]*wka.w
              + xn[4]*wkb.x + xn[5]*wkb.y + xn[6]*wkb.z + xn[7]*wkb.w;
    #pragma unroll
    for (int off = 1; off < 8; off <<= 1) {
        pq  += __shfl_xor(pq, off);
        pkv += __shfl_xor(pkv, off);
    }
    if ((lane & 7) == 0) {
        int bh = b * Hsz + h;
        Qo[bh * Ssz + s] = pq + bq[h];
        Ko[bh * Ssz + s] = pkv + bk[h];
    }
}

// ---------------- K2a: G partials:  Gp[bh][chunk][n][68] = sum_k w_n(k) xh[k,:] (+den at col64) ----------------
__global__ __launch_bounds__(256) void attn_moments(
    const float* __restrict__ Kv, const __hip_bfloat16* __restrict__ Xn, float* __restrict__ Gp)
{
    int chunk = blockIdx.x, bh = blockIdx.y;
    int t = threadIdx.x;
    __shared__ float Wt[CHK][17];
    __shared__ float denp[4][16];

    if (t < CHK) {
        float kv = Kv[bh * Ssz + chunk * CHK + t];
        float wn = __expf(-0.125f * kv * kv);
        float half = 0.5f * kv;
        Wt[t][0] = wn;
        #pragma unroll
        for (int n = 1; n < NR; ++n) { wn *= half * RS[n]; Wt[t][n] = wn; }
    }
    __syncthreads();

    int w = t >> 6, lane = t & 63;
    int ng = w * 4;
    float a0 = 0.f, a1 = 0.f, a2 = 0.f, a3 = 0.f;
    const __hip_bfloat16* xb = Xn + ((size_t)bh * Ssz + chunk * CHK) * Dsz + lane;
    for (int k = 0; k < CHK; ++k) {
        float v = __bfloat162float(xb[(size_t)k * Dsz]);
        a0 = fmaf(Wt[k][ng + 0], v, a0);
        a1 = fmaf(Wt[k][ng + 1], v, a1);
        a2 = fmaf(Wt[k][ng + 2], v, a2);
        a3 = fmaf(Wt[k][ng + 3], v, a3);
    }
    size_t base = (((size_t)bh * NCH + chunk) * NR + ng) * 68 + lane;
    Gp[base + 0 * 68] = a0;
    Gp[base + 1 * 68] = a1;
    Gp[base + 2 * 68] = a2;
    Gp[base + 3 * 68] = a3;

    if (t < 64) {
        int n = t & 15, q = t >> 4;
        float s = 0.f;
        #pragma unroll
        for (int kk = 0; kk < CHK / 4; ++kk) s += Wt[q * (CHK / 4) + kk][n];
        denp[q][n] = s;
    }
    __syncthreads();
    if (t < 16) {
        float m = denp[0][t] + denp[1][t] + denp[2][t] + denp[3][t];
        Gp[(((size_t)bh * NCH + chunk) * NR + t) * 68 + 64] = m;
    }
}

// ---------------- K2b: reduce chunks + apply Wv:  M[n,d] = G[n,:]@Wv[h][:,d] + den_n*bv ----------------
__global__ __launch_bounds__(256) void attn_mtransform(
    const float* __restrict__ Gp, const float* __restrict__ Wv, const float* __restrict__ bv,
    float* __restrict__ M)
{
    int bh = blockIdx.x, h = bh & 7, t = threadIdx.x;
    __shared__ float Gf[NR * 68];
    for (int i = t; i < NR * 68; i += 256) {
        float s = 0.f;
        #pragma unroll
        for (int c = 0; c < NCH; ++c)
            s += Gp[(((size_t)bh * NCH + c) * NR) * 68 + i];
        Gf[i] = s;
    }
    __syncthreads();
    #pragma unroll
    for (int rep = 0; rep < 4; ++rep) {
        int o = t + rep * 256;
        int n = o >> 6, dd = o & 63;
        float den = Gf[n * 68 + 64];
        float acc = den * bv[h * 64 + dd];
        const float* wv = Wv + ((size_t)h * 64) * 64 + dd;
        #pragma unroll
        for (int e = 0; e < 64; ++e) acc = fmaf(Gf[n * 68 + e], wv[(size_t)e * 64], acc);
        M[(size_t)bh * NR * 68 + n * 68 + dd] = acc;
        if (dd == 0) M[(size_t)bh * NR * 68 + n * 68 + 64] = den;
    }
}

// ---------------- K2c: apply Q-side, write head_out as bf16 [8192,512] ----------------
__global__ __launch_bounds__(256) void attn_apply(
    const float* __restrict__ Qv, const float* __restrict__ M, __hip_bfloat16* __restrict__ A1)
{
    int tok = blockIdx.x;
    int b = tok >> 11, s = tok & 2047;
    int t = threadIdx.x;
    #pragma unroll
    for (int rep = 0; rep < 2; ++rep) {
        int e = t + rep * 256;
        int h = e >> 6, dd = e & 63;
        int bh = b * 8 + h;
        float q = Qv[bh * Ssz + s];
        const float* Mb = M + (size_t)bh * NR * 68;
        float half = 0.5f * q;
        float phi = 1.0f;
        float num = Mb[dd], den = Mb[64];
        #pragma unroll
        for (int n = 1; n < NR; ++n) {
            phi *= half * RS[n];
            num = fmaf(phi, Mb[n * 68 + dd], num);
            den = fmaf(phi, Mb[n * 68 + 64], den);
        }
        A1[(size_t)tok * Esz + e] = __float2bfloat16(num / den);
    }
}

// ---------------- transpose + fp32->bf16: out[C][R] = in[R][C] ----------------
__global__ __launch_bounds__(256) void transpose_bf16(
    const float* __restrict__ in, __hip_bfloat16* __restrict__ out, int R, int C)
{
    __shared__ float tile[32][33];
    int bx = blockIdx.x, by = blockIdx.y;
    int t = threadIdx.x;
    int tc = t & 31, tr = t >> 5;
    #pragma unroll
    for (int i = 0; i < 4; ++i) {
        int r = by * 32 + tr + i * 8, c = bx * 32 + tc;
        tile[tr + i * 8][tc] = in[(size_t)r * C + c];
    }
    __syncthreads();
    #pragma unroll
    for (int i = 0; i < 4; ++i) {
        int ro = bx * 32 + tr + i * 8, co = by * 32 + tc;
        out[(size_t)ro * R + co] = __float2bfloat16(tile[tc][tr + i * 8]);
    }
}

// ---------------- bf16 MFMA GEMM: C = A[M,K] * Bt[N,K]^T, 128x128 tile, BK=32 ----------------
template <int KDIM, int EPI>
__global__ __launch_bounds__(256) void gemm_bf16(
    const __hip_bfloat16* __restrict__ A, const __hip_bfloat16* __restrict__ Bt,
    const float* __restrict__ bias, const float* __restrict__ resid,
    void* __restrict__ Out, int N)
{
    __shared__ unsigned short As[128][32];
    __shared__ unsigned short Bs[128][32];
    int t = threadIdx.x;
    int w = t >> 6, lane = t & 63;
    int wr = w >> 1, wc = w & 1;
    int bm = blockIdx.y * 128, bn = blockIdx.x * 128;

    f32x4 acc[4][4] = {};
    const int r = t >> 2, cg = (t & 3) * 8;

    for (int k0 = 0; k0 < KDIM; k0 += 32) {
        gload_lds16(&A[(size_t)(bm + r) * KDIM + k0 + cg], &As[r][cg]);
        gload_lds16(&A[(size_t)(bm + r + 64) * KDIM + k0 + cg], &As[r + 64][cg]);
        gload_lds16(&Bt[(size_t)(bn + r) * KDIM + k0 + cg], &Bs[r][cg]);
        gload_lds16(&Bt[(size_t)(bn + r + 64) * KDIM + k0 + cg], &Bs[r + 64][cg]);
        __syncthreads();
        bf16x8 af[4], bfr[4];
        #pragma unroll
        for (int i = 0; i < 4; ++i) {
            af[i]  = *(const bf16x8*)&As[wr * 64 + i * 16 + (lane & 15)][(lane >> 4) * 8];
            bfr[i] = *(const bf16x8*)&Bs[wc * 64 + i * 16 + (lane & 15)][(lane >> 4) * 8];
        }
        #pragma unroll
        for (int i = 0; i < 4; ++i)
            #pragma unroll
            for (int j = 0; j < 4; ++j)
                acc[i][j] = __builtin_amdgcn_mfma_f32_16x16x32_bf16(af[i], bfr[j], acc[i][j], 0, 0, 0);
        __syncthreads();
    }

    int col0 = lane & 15, rowg = lane >> 4;
    #pragma unroll
    for (int i = 0; i < 4; ++i) {
        #pragma unroll
        for (int j = 0; j < 4; ++j) {
            #pragma unroll
            for (int v = 0; v < 4; ++v) {
                int m = bm + wr * 64 + i * 16 + rowg * 4 + v;
                int n = bn + wc * 64 + j * 16 + col0;
                float val = acc[i][j][v] + bias[n];
                if (EPI == 0) {
                    float g = 0.5f * val * (1.0f + erff(val * 0.70710678f));
                    ((__hip_bfloat16*)Out)[(size_t)m * N + n] = __float2bfloat16(g);
                } else {
                    size_t idx = (size_t)m * N + n;
                    ((float*)Out)[idx] = val + resid[idx];
                }
            }
        }
    }
}

extern "C" void kernel_launch(void* const* d_in, const int* in_sizes, int n_in,
                              void* d_out, int out_size, void* d_ws, size_t ws_size,
                              hipStream_t stream) {
    const float* x  = (const float*)d_in[0];
    const float* Wv = (const float*)d_in[1];
    const float* bv = (const float*)d_in[2];
    const float* Wq = (const float*)d_in[3];
    const float* bq = (const float*)d_in[4];
    const float* Wk = (const float*)d_in[5];
    const float* bk = (const float*)d_in[6];
    const float* W1 = (const float*)d_in[7];
    const float* b1 = (const float*)d_in[8];
    const float* W2 = (const float*)d_in[9];
    const float* b2 = (const float*)d_in[10];
    float* out = (float*)d_out;

    char* ws = (char*)d_ws;
    float* Qb    = (float*)(ws + 0);                     // 256 KB
    float* Kb    = (float*)(ws + 262144);                // 256 KB
    __hip_bfloat16* Xn = (__hip_bfloat16*)(ws + 524288); // 8 MB  [bh][s][d]
    float* Gp    = (float*)(ws + 8912896);               // 32*16*16*68*4 = 2.23 MB
    float* Mfull = (float*)(ws + 11141120);              // 139 KB
    __hip_bfloat16* A1   = (__hip_bfloat16*)(ws + 11280384); // 8 MB
    __hip_bfloat16* W1T  = (__hip_bfloat16*)(ws + 19668992); // 2 MB
    __hip_bfloat16* W2T  = (__hip_bfloat16*)(ws + 21766144); // 2 MB
    __hip_bfloat16* hbuf = (__hip_bfloat16*)(ws + 23863296); // 32 MB

    ln_qk_kernel<<<dim3((Bsz * Ssz) / 4), 256, 0, stream>>>(x, Wq, bq, Wk, bk, Qb, Kb, Xn);
    attn_moments<<<dim3(NCH, Bsz * Hsz), 256, 0, stream>>>(Kb, Xn, Gp);
    attn_mtransform<<<dim3(Bsz * Hsz), 256, 0, stream>>>(Gp, Wv, bv, Mfull);
    attn_apply<<<dim3(Bsz * Ssz), 256, 0, stream>>>(Qb, Mfull, A1);
    transpose_bf16<<<dim3(Fsz / 32, Esz / 32), 256, 0, stream>>>(W1, W1T, Esz, Fsz);
    transpose_bf16<<<dim3(Esz / 32, Fsz / 32), 256, 0, stream>>>(W2, W2T, Fsz, Esz);
    gemm_bf16<Esz, 0><<<dim3(Fsz / 128, (Bsz * Ssz) / 128), 256, 0, stream>>>(A1, W1T, b1, nullptr, hbuf, Fsz);
    gemm_bf16<Fsz, 1><<<dim3(Esz / 128, (Bsz * Ssz) / 128), 256, 0, stream>>>(hbuf, W2T, b2, x, out, Esz);
}